// Round 10
// baseline (222.713 us; speedup 1.0000x reference)
//
#include <hip/hip_runtime.h>

#define N_NODES 50000
#define N_EDGES 800000
#define C 128
#define BN_EPS 1e-5f
#define BSHIFT 7                              // 128 nodes per bucket
#define NBUCK ((N_NODES + 127) >> BSHIFT)     // 391
#define EPB 4096                              // edges per block (phase A)
#define A_BLOCKS ((N_EDGES + EPB - 1) / EPB)  // 196
#define GB ((N_NODES + 15) / 16)              // 3125 gather blocks (exact: 3125*16=50000)

typedef __attribute__((ext_vector_type(8))) short bf16x8;
typedef __attribute__((ext_vector_type(4))) float f32x4;

__device__ __forceinline__ unsigned pack_bf16x2(float a, float b) {
    unsigned ua = __float_as_uint(a);
    ua = (ua + 0x7FFFu + ((ua >> 16) & 1u)) >> 16;   // RNE
    unsigned ub = __float_as_uint(b);
    ub = (ub + 0x7FFFu + ((ub >> 16) & 1u)) >> 16;
    return ua | (ub << 16);
}

__device__ __forceinline__ unsigned short bf16_1(float a) {
    unsigned u = __float_as_uint(a);
    return (unsigned short)((u + 0x7FFFu + ((u >> 16) & 1u)) >> 16);
}

__device__ __forceinline__ float blo(unsigned u) { return __uint_as_float(u << 16); }
__device__ __forceinline__ float bhi(unsigned u) { return __uint_as_float(u & 0xFFFF0000u); }

// ---- phase A1: coarse bucket histogram (saved per-block to bHistG);
//      block 0 also builds WTg = bf16(W^T) ----
__global__ void __launch_bounds__(256) k_bhist(const int* __restrict__ col,
                                               int* __restrict__ bCnt,
                                               int* __restrict__ bHistG,
                                               const float* __restrict__ W,
                                               unsigned* __restrict__ WTg) {
    __shared__ int hist[NBUCK];
    for (int i = threadIdx.x; i < NBUCK; i += 256) hist[i] = 0;
    __syncthreads();
    int e0 = blockIdx.x * EPB;
    int e1 = e0 + EPB; if (e1 > N_EDGES) e1 = N_EDGES;
    for (int e = e0 + threadIdx.x; e < e1; e += 256)
        atomicAdd(&hist[col[e] >> BSHIFT], 1);
    if (blockIdx.x == 0) {
        // WTg dword j of row n holds bf16(W[2j][n]) | bf16(W[2j+1][n])<<16
#pragma unroll
        for (int it = 0; it < 32; ++it) {
            int i = threadIdx.x + (it << 8);
            int kh = i & 63, n = i >> 6;
            WTg[n * 64 + kh] = pack_bf16x2(W[(kh * 2) * C + n], W[(kh * 2 + 1) * C + n]);
        }
    }
    __syncthreads();
    int* hrow = bHistG + blockIdx.x * NBUCK;
    for (int i = threadIdx.x; i < NBUCK; i += 256) {
        int h = hist[i];
        hrow[i] = h;
        if (h) atomicAdd(&bCnt[i], h);
    }
}

// ---- bucket scan: bStart/bCur = exclusive scan of bCnt ----
__global__ void __launch_bounds__(512) k_bscan(const int* __restrict__ bCnt,
                                               int* __restrict__ bStart,
                                               int* __restrict__ bCur,
                                               int* __restrict__ offs) {
    __shared__ int ws[8];
    int t = threadIdx.x, lane = t & 63, wid = t >> 6;
    int v = (t < NBUCK) ? bCnt[t] : 0;
    int sc = v;
#pragma unroll
    for (int d = 1; d < 64; d <<= 1) {
        int u = __shfl_up(sc, d, 64);
        if (lane >= d) sc += u;
    }
    if (lane == 63) ws[wid] = sc;
    __syncthreads();
    int add = 0;
    for (int w = 0; w < wid; ++w) add += ws[w];
    if (t < NBUCK) { int ex = add + sc - v; bStart[t] = ex; bCur[t] = ex; }
    if (t == 0) { bStart[NBUCK] = N_EDGES; offs[N_NODES] = N_EDGES; }
}

// ---- phase A2: scatter packed edges (src | dst<<16) into coarse buckets;
//      per-block histogram comes precomputed from bHistG ----
__global__ void __launch_bounds__(256) k_bscatter(const int* __restrict__ row,
                                                  const int* __restrict__ col,
                                                  const int* __restrict__ bHistG,
                                                  int* __restrict__ bCur,
                                                  unsigned* __restrict__ bEdges) {
    __shared__ int hist[NBUCK];
    __shared__ int lbase[NBUCK];
    const int* hrow = bHistG + blockIdx.x * NBUCK;
    for (int i = threadIdx.x; i < NBUCK; i += 256) {
        int h = hrow[i];
        lbase[i] = h ? atomicAdd(&bCur[i], h) : 0;
        hist[i] = 0;
    }
    __syncthreads();
    int e0 = blockIdx.x * EPB;
    int e1 = e0 + EPB; if (e1 > N_EDGES) e1 = N_EDGES;
    for (int e = e0 + threadIdx.x; e < e1; e += 256) {
        int d = col[e];
        int b = d >> BSHIFT;
        int r = atomicAdd(&hist[b], 1);
        bEdges[lbase[b] + r] = (unsigned)row[e] | ((unsigned)d << 16);
    }
}

// ---- phase B: per-bucket node histogram + scan -> offs/cnt, scatter srcs ----
__global__ void __launch_bounds__(256) k_bsort(const unsigned* __restrict__ bEdges,
                                               const int* __restrict__ bStart,
                                               int* __restrict__ offs,
                                               int* __restrict__ cnt,
                                               unsigned short* __restrict__ srcs) {
    __shared__ int h[128];
    __shared__ int wtot;
    int tid = threadIdx.x;
    int b = blockIdx.x;
    int n0 = b << BSHIFT;
    int nn = N_NODES - n0; if (nn > 128) nn = 128;
    int e0 = bStart[b], e1 = bStart[b + 1];
    if (tid < 128) h[tid] = 0;
    __syncthreads();
    for (int e = e0 + tid; e < e1; e += 256)
        atomicAdd(&h[(int)(bEdges[e] >> 16) - n0], 1);
    __syncthreads();
    int v = 0, sc = 0;
    if (tid < 128) {
        int lane = tid & 63;
        v = h[tid];
        sc = v;
#pragma unroll
        for (int d = 1; d < 64; d <<= 1) {
            int u = __shfl_up(sc, d, 64);
            if (lane >= d) sc += u;
        }
        if (tid == 63) wtot = sc;
    }
    __syncthreads();
    if (tid < 128) {
        int ex = sc - v + ((tid >= 64) ? wtot : 0);
        if (tid < nn) { offs[n0 + tid] = e0 + ex; cnt[n0 + tid] = v; }
        h[tid] = ex;  // reuse as cursor
    }
    __syncthreads();
    for (int e = e0 + tid; e < e1; e += 256) {
        unsigned pe = bEdges[e];
        int r = atomicAdd(&h[(int)(pe >> 16) - n0], 1);
        srcs[e0 + r] = (unsigned short)(pe & 0xFFFFu);
    }
}

// ---- g(bf16) = dinv[row]*(x@W) via MFMA 16x16x32 bf16 ----
__global__ void __launch_bounds__(256) k_gemm(const float* __restrict__ x,
                                              const unsigned* __restrict__ WTg,
                                              const int* __restrict__ cnt,
                                              unsigned short* __restrict__ g) {
    __shared__ unsigned xs[64 * 68];  // 64 rows x 68 dwords (128 bf16 + pad)
    int tid = threadIdx.x;
    int r0 = blockIdx.x * 64;
    const float4* x4 = (const float4*)x;
#pragma unroll
    for (int it = 0; it < 8; ++it) {
        int i = tid + (it << 8);
        int row = i >> 5, c4 = i & 31;
        float4 v = {0.f, 0.f, 0.f, 0.f};
        if (r0 + row < N_NODES) v = x4[(size_t)(r0 + row) * 32 + c4];
        xs[row * 68 + c4 * 2]     = pack_bf16x2(v.x, v.y);
        xs[row * 68 + c4 * 2 + 1] = pack_bf16x2(v.z, v.w);
    }
    __syncthreads();
    int wave = tid >> 6, lane = tid & 63;
    int r0w = r0 + wave * 16;
    if (r0w >= N_NODES) return;
    int m = lane & 15, q = lane >> 4;
    bf16x8 afrag[4];
#pragma unroll
    for (int kt = 0; kt < 4; ++kt)
        afrag[kt] = *(const bf16x8*)&xs[(wave * 16 + m) * 68 + kt * 16 + q * 4];
    const uint4* B4 = (const uint4*)WTg;
    int bbase = m * 16 + q;
    f32x4 acc[8];
#pragma unroll
    for (int nt = 0; nt < 8; ++nt)
        acc[nt][0] = acc[nt][1] = acc[nt][2] = acc[nt][3] = 0.f;
#pragma unroll
    for (int nt = 0; nt < 8; ++nt) {
#pragma unroll
        for (int kt = 0; kt < 4; ++kt) {
            uint4 braw = B4[nt * 256 + kt * 4 + bbase];
            bf16x8 bfrag = __builtin_bit_cast(bf16x8, braw);
            acc[nt] = __builtin_amdgcn_mfma_f32_16x16x32_bf16(afrag[kt], bfrag, acc[nt], 0, 0, 0);
        }
    }
    int rb = r0w + q * 4;
    float dv[4];
#pragma unroll
    for (int reg = 0; reg < 4; ++reg) dv[reg] = rsqrtf((float)cnt[rb + reg] + 1.f);
#pragma unroll
    for (int nt = 0; nt < 8; ++nt) {
        int cbase = nt * 16 + m;
#pragma unroll
        for (int reg = 0; reg < 4; ++reg)
            g[(size_t)(rb + reg) * C + cbase] = bf16_1(acc[nt][reg] * dv[reg]);
    }
}

// ---- gather: 16 lanes per node, 4 nodes per wave, uint4 row segments ----
// Fused BN-stats: per-block partial sum/sumsq written atomic-free to partials.
// N_NODES = 3125*16 exactly: every thread owns a live node (no tail).
__global__ void __launch_bounds__(256) k_gather(const int* __restrict__ offs,
                                                const unsigned short* __restrict__ srcs,
                                                const uint4* __restrict__ g4,
                                                float* __restrict__ agg,
                                                float* __restrict__ partials) {
    int t = threadIdx.x;
    int node = blockIdx.x * 16 + (t >> 4);
    int l = t & 15;          // lane within quarter
    int qb = t & 48;         // quarter base within wave (0,16,32,48)
    int beg = offs[node], end = offs[node + 1];
    uint4 u = g4[(size_t)node * 16 + l];  // self-loop term
    float a0[8], a1[8], a2[8], a3[8];
    a0[0] = blo(u.x); a0[1] = bhi(u.x); a0[2] = blo(u.y); a0[3] = bhi(u.y);
    a0[4] = blo(u.z); a0[5] = bhi(u.z); a0[6] = blo(u.w); a0[7] = bhi(u.w);
#pragma unroll
    for (int i = 0; i < 8; ++i) { a1[i] = 0.f; a2[i] = 0.f; a3[i] = 0.f; }
    for (int base = beg; base < end; base += 16) {
        int m = end - base; if (m > 16) m = 16;
        int sv = (base + l < end) ? (int)srcs[base + l] : 0;  // 16-wide batch
        int j = 0;
        for (; j + 3 < m; j += 4) {
            int s0 = __shfl(sv, qb + j, 64);
            int s1 = __shfl(sv, qb + j + 1, 64);
            int s2 = __shfl(sv, qb + j + 2, 64);
            int s3 = __shfl(sv, qb + j + 3, 64);
            uint4 v0 = g4[(size_t)s0 * 16 + l];
            uint4 v1 = g4[(size_t)s1 * 16 + l];
            uint4 v2 = g4[(size_t)s2 * 16 + l];
            uint4 v3 = g4[(size_t)s3 * 16 + l];
            a0[0] += blo(v0.x); a0[1] += bhi(v0.x); a0[2] += blo(v0.y); a0[3] += bhi(v0.y);
            a0[4] += blo(v0.z); a0[5] += bhi(v0.z); a0[6] += blo(v0.w); a0[7] += bhi(v0.w);
            a1[0] += blo(v1.x); a1[1] += bhi(v1.x); a1[2] += blo(v1.y); a1[3] += bhi(v1.y);
            a1[4] += blo(v1.z); a1[5] += bhi(v1.z); a1[6] += blo(v1.w); a1[7] += bhi(v1.w);
            a2[0] += blo(v2.x); a2[1] += bhi(v2.x); a2[2] += blo(v2.y); a2[3] += bhi(v2.y);
            a2[4] += blo(v2.z); a2[5] += bhi(v2.z); a2[6] += blo(v2.w); a2[7] += bhi(v2.w);
            a3[0] += blo(v3.x); a3[1] += bhi(v3.x); a3[2] += blo(v3.y); a3[3] += bhi(v3.y);
            a3[4] += blo(v3.z); a3[5] += bhi(v3.z); a3[6] += blo(v3.w); a3[7] += bhi(v3.w);
        }
        for (; j < m; ++j) {
            int s0 = __shfl(sv, qb + j, 64);
            uint4 v0 = g4[(size_t)s0 * 16 + l];
            a0[0] += blo(v0.x); a0[1] += bhi(v0.x); a0[2] += blo(v0.y); a0[3] += bhi(v0.y);
            a0[4] += blo(v0.z); a0[5] += bhi(v0.z); a0[6] += blo(v0.w); a0[7] += bhi(v0.w);
        }
    }
    float dt = rsqrtf((float)(end - beg) + 1.f);
    float v16[16];
#pragma unroll
    for (int i = 0; i < 8; ++i) {
        v16[i] = (a0[i] + a1[i] + a2[i] + a3[i]) * dt;
        v16[8 + i] = v16[i] * v16[i];
    }
    float4* out = (float4*)(agg + (size_t)node * C + l * 8);
    out[0] = make_float4(v16[0], v16[1], v16[2], v16[3]);
    out[1] = make_float4(v16[4], v16[5], v16[6], v16[7]);
    // ---- stats reduction: xor16/xor32 combine the wave's 4 nodes ----
#pragma unroll
    for (int i = 0; i < 16; ++i) {
        v16[i] += __shfl_xor(v16[i], 16, 64);
        v16[i] += __shfl_xor(v16[i], 32, 64);
    }
    __shared__ float ls[4][16][16];
    int wv = t >> 6, tl = t & 63;
    if (tl < 16) {
#pragma unroll
        for (int v = 0; v < 16; ++v) ls[wv][tl][v] = v16[v];
    }
    __syncthreads();
    {
        int l2 = t >> 4, v2 = t & 15;
        float s = (ls[0][l2][v2] + ls[1][l2][v2]) + (ls[2][l2][v2] + ls[3][l2][v2]);
        // idx: [0..127]=sum(channel), [128..255]=sumsq(channel); channel = 8*l2 + (v2&7)
        int off = ((v2 & 8) ? 128 : 0) + l2 * 8 + (v2 & 7);
        partials[(size_t)blockIdx.x * 256 + off] = s;
    }
}

// ---- reduce 3125 partial rows -> sums[0..127], sumsq[128..255] ----
__global__ void __launch_bounds__(256) k_red(const float* __restrict__ partials,
                                             float* __restrict__ sums) {
    float acc = 0.f;
    for (int r = blockIdx.x; r < GB; r += 32)
        acc += partials[(size_t)r * 256 + threadIdx.x];
    atomicAdd(&sums[threadIdx.x], acc);
}

// ---- y = relu(agg*scale + shift); bias cancels in BN ----
__global__ void __launch_bounds__(256) k_final(float* __restrict__ agg,
                                               const float* __restrict__ sums,
                                               const float* __restrict__ sumsq,
                                               const float* __restrict__ gamma,
                                               const float* __restrict__ beta) {
    __shared__ float sc_s[C], sh_s[C];
    int tid = threadIdx.x;
    if (tid < C) {
        float mean = sums[tid] * (1.0f / N_NODES);
        float var = sumsq[tid] * (1.0f / N_NODES) - mean * mean;
        float sc = gamma[tid] * rsqrtf(var + BN_EPS);
        sc_s[tid] = sc;
        sh_s[tid] = beta[tid] - mean * sc;
    }
    __syncthreads();
    int i = blockIdx.x * 256 + tid;
    if (i >= N_NODES * 32) return;
    int c = (i & 31) * 4;
    float4 v = ((float4*)agg)[i];
    v.x = fmaxf(v.x * sc_s[c + 0] + sh_s[c + 0], 0.f);
    v.y = fmaxf(v.y * sc_s[c + 1] + sh_s[c + 1], 0.f);
    v.z = fmaxf(v.z * sc_s[c + 2] + sh_s[c + 2], 0.f);
    v.w = fmaxf(v.w * sc_s[c + 3] + sh_s[c + 3], 0.f);
    ((float4*)agg)[i] = v;
}

extern "C" void kernel_launch(void* const* d_in, const int* in_sizes, int n_in,
                              void* d_out, int out_size, void* d_ws, size_t ws_size,
                              hipStream_t stream) {
    const float* x     = (const float*)d_in[0];
    const float* W     = (const float*)d_in[1];
    // d_in[2] = bias: cancels in BatchNorm, unused
    const float* gamma = (const float*)d_in[3];
    const float* beta  = (const float*)d_in[4];
    const int*   eidx  = (const int*)d_in[5];
    const int* row = eidx;
    const int* col = eidx + N_EDGES;

    float* agg = (float*)d_out;  // [N, C], finalized in place

    // workspace layout — [sums|sumsq|bCnt] contiguous for a single memset
    unsigned* g      = (unsigned*)d_ws;                  // [N*64] bf16x2
    unsigned* bEdges = g + (size_t)N_NODES * 64;         // [E] packed src|dst<<16
    int*   cnt    = (int*)(bEdges + N_EDGES);            // [N]
    int*   offs   = cnt + N_NODES;                       // [N+1]
    float* sums   = (float*)(offs + N_NODES + 1);        // [C]   (zeroed)
    float* sumsq  = sums + C;                            // [C]   (zeroed)
    int*   bCnt   = (int*)(sumsq + C);                   // [NBUCK+1] (zeroed)
    int*   bStart = bCnt + NBUCK + 1;                    // [NBUCK+1]
    int*   bCur   = bStart + NBUCK + 1;                  // [NBUCK]
    int*   bHistG = bCur + NBUCK;                        // [A_BLOCKS*NBUCK]
    unsigned* WTg = (unsigned*)(bHistG + A_BLOCKS * NBUCK); // [128*64] bf16x2 (W^T)
    unsigned short* srcs = (unsigned short*)(WTg + 128 * 64); // [E] u16
    float* partials = (float*)(srcs + N_EDGES);          // [GB*256]

    hipMemsetAsync(sums, 0, (2 * C + NBUCK + 1) * sizeof(int), stream);

    k_bhist<<<A_BLOCKS, 256, 0, stream>>>(col, bCnt, bHistG, W, WTg);
    k_bscan<<<1, 512, 0, stream>>>(bCnt, bStart, bCur, offs);
    k_bscatter<<<A_BLOCKS, 256, 0, stream>>>(row, col, bHistG, bCur, bEdges);
    k_bsort<<<NBUCK, 256, 0, stream>>>(bEdges, bStart, offs, cnt, srcs);
    k_gemm<<<(N_NODES + 63) / 64, 256, 0, stream>>>(x, WTg, cnt, (unsigned short*)g);
    k_gather<<<GB, 256, 0, stream>>>(offs, srcs, (const uint4*)g, agg, partials);
    k_red<<<32, 256, 0, stream>>>(partials, sums);
    k_final<<<(N_NODES * 32 + 255) / 256, 256, 0, stream>>>(agg, sums, sumsq, gamma, beta);
}

// Round 11
// 218.930 us; speedup vs baseline: 1.0173x; 1.0173x over previous
//
#include <hip/hip_runtime.h>

#define N_NODES 50000
#define N_EDGES 800000
#define C 128
#define BN_EPS 1e-5f
#define BSHIFT 7                              // 128 nodes per bucket
#define NBUCK ((N_NODES + 127) >> BSHIFT)     // 391
#define EPB 4096                              // edges per block (phase A)
#define A_BLOCKS ((N_EDGES + EPB - 1) / EPB)  // 196

typedef __attribute__((ext_vector_type(8))) short bf16x8;
typedef __attribute__((ext_vector_type(4))) float f32x4;

__device__ __forceinline__ unsigned pack_bf16x2(float a, float b) {
    unsigned ua = __float_as_uint(a);
    ua = (ua + 0x7FFFu + ((ua >> 16) & 1u)) >> 16;   // RNE
    unsigned ub = __float_as_uint(b);
    ub = (ub + 0x7FFFu + ((ub >> 16) & 1u)) >> 16;
    return ua | (ub << 16);
}

__device__ __forceinline__ unsigned short bf16_1(float a) {
    unsigned u = __float_as_uint(a);
    return (unsigned short)((u + 0x7FFFu + ((u >> 16) & 1u)) >> 16);
}

__device__ __forceinline__ float blo(unsigned u) { return __uint_as_float(u << 16); }
__device__ __forceinline__ float bhi(unsigned u) { return __uint_as_float(u & 0xFFFF0000u); }

// ---- phase A1: per-block coarse bucket histogram -> bHistG;
//      block 0 also builds WTg = bf16(W^T). No global atomics. ----
__global__ void __launch_bounds__(256) k_bhist(const int* __restrict__ col,
                                               int* __restrict__ bHistG,
                                               const float* __restrict__ W,
                                               unsigned* __restrict__ WTg) {
    __shared__ int hist[NBUCK];
    for (int i = threadIdx.x; i < NBUCK; i += 256) hist[i] = 0;
    __syncthreads();
    int e0 = blockIdx.x * EPB;
    int e1 = e0 + EPB; if (e1 > N_EDGES) e1 = N_EDGES;
    for (int e = e0 + threadIdx.x; e < e1; e += 256)
        atomicAdd(&hist[col[e] >> BSHIFT], 1);
    if (blockIdx.x == 0) {
        // WTg dword j of row n holds bf16(W[2j][n]) | bf16(W[2j+1][n])<<16
#pragma unroll
        for (int it = 0; it < 32; ++it) {
            int i = threadIdx.x + (it << 8);
            int kh = i & 63, n = i >> 6;
            WTg[n * 64 + kh] = pack_bf16x2(W[(kh * 2) * C + n], W[(kh * 2 + 1) * C + n]);
        }
    }
    __syncthreads();
    int* hrow = bHistG + blockIdx.x * NBUCK;
    for (int i = threadIdx.x; i < NBUCK; i += 256) hrow[i] = hist[i];
}

// ---- bucket scan: column-sum bHistG -> bucket counts -> exclusive scan.
//      Also zeroes the BN accumulators (sums[0..127]|sumsq[128..255]). ----
__global__ void __launch_bounds__(512) k_bscan(const int* __restrict__ bHistG,
                                               int* __restrict__ bStart,
                                               int* __restrict__ bCur,
                                               int* __restrict__ offs,
                                               float* __restrict__ sums) {
    __shared__ int ws[8];
    int t = threadIdx.x, lane = t & 63, wid = t >> 6;
    if (t < 256) sums[t] = 0.f;  // zero sums+sumsq (contiguous)
    int v = 0;
    if (t < NBUCK)
        for (int w = 0; w < A_BLOCKS; ++w) v += bHistG[w * NBUCK + t];
    int sc = v;
#pragma unroll
    for (int d = 1; d < 64; d <<= 1) {
        int u = __shfl_up(sc, d, 64);
        if (lane >= d) sc += u;
    }
    if (lane == 63) ws[wid] = sc;
    __syncthreads();
    int add = 0;
    for (int w = 0; w < wid; ++w) add += ws[w];
    if (t < NBUCK) { int ex = add + sc - v; bStart[t] = ex; bCur[t] = ex; }
    if (t == 0) { bStart[NBUCK] = N_EDGES; offs[N_NODES] = N_EDGES; }
}

// ---- phase A2: scatter packed edges (src | dst<<16) into coarse buckets;
//      per-block histogram comes precomputed from bHistG ----
__global__ void __launch_bounds__(256) k_bscatter(const int* __restrict__ row,
                                                  const int* __restrict__ col,
                                                  const int* __restrict__ bHistG,
                                                  int* __restrict__ bCur,
                                                  unsigned* __restrict__ bEdges) {
    __shared__ int hist[NBUCK];
    __shared__ int lbase[NBUCK];
    const int* hrow = bHistG + blockIdx.x * NBUCK;
    for (int i = threadIdx.x; i < NBUCK; i += 256) {
        int h = hrow[i];
        lbase[i] = h ? atomicAdd(&bCur[i], h) : 0;
        hist[i] = 0;
    }
    __syncthreads();
    int e0 = blockIdx.x * EPB;
    int e1 = e0 + EPB; if (e1 > N_EDGES) e1 = N_EDGES;
    for (int e = e0 + threadIdx.x; e < e1; e += 256) {
        int d = col[e];
        int b = d >> BSHIFT;
        int r = atomicAdd(&hist[b], 1);
        bEdges[lbase[b] + r] = (unsigned)row[e] | ((unsigned)d << 16);
    }
}

// ---- phase B: per-bucket node histogram + scan -> offs/cnt, scatter srcs ----
__global__ void __launch_bounds__(256) k_bsort(const unsigned* __restrict__ bEdges,
                                               const int* __restrict__ bStart,
                                               int* __restrict__ offs,
                                               int* __restrict__ cnt,
                                               unsigned short* __restrict__ srcs) {
    __shared__ int h[128];
    __shared__ int wtot;
    int tid = threadIdx.x;
    int b = blockIdx.x;
    int n0 = b << BSHIFT;
    int nn = N_NODES - n0; if (nn > 128) nn = 128;
    int e0 = bStart[b], e1 = bStart[b + 1];
    if (tid < 128) h[tid] = 0;
    __syncthreads();
    for (int e = e0 + tid; e < e1; e += 256)
        atomicAdd(&h[(int)(bEdges[e] >> 16) - n0], 1);
    __syncthreads();
    int v = 0, sc = 0;
    if (tid < 128) {
        int lane = tid & 63;
        v = h[tid];
        sc = v;
#pragma unroll
        for (int d = 1; d < 64; d <<= 1) {
            int u = __shfl_up(sc, d, 64);
            if (lane >= d) sc += u;
        }
        if (tid == 63) wtot = sc;
    }
    __syncthreads();
    if (tid < 128) {
        int ex = sc - v + ((tid >= 64) ? wtot : 0);
        if (tid < nn) { offs[n0 + tid] = e0 + ex; cnt[n0 + tid] = v; }
        h[tid] = ex;  // reuse as cursor
    }
    __syncthreads();
    for (int e = e0 + tid; e < e1; e += 256) {
        unsigned pe = bEdges[e];
        int r = atomicAdd(&h[(int)(pe >> 16) - n0], 1);
        srcs[e0 + r] = (unsigned short)(pe & 0xFFFFu);
    }
}

// ---- g(bf16) = dinv[row]*(x@W) via MFMA 16x16x32 bf16 ----
__global__ void __launch_bounds__(256) k_gemm(const float* __restrict__ x,
                                              const unsigned* __restrict__ WTg,
                                              const int* __restrict__ cnt,
                                              unsigned short* __restrict__ g) {
    __shared__ unsigned xs[64 * 68];  // 64 rows x 68 dwords (128 bf16 + pad)
    int tid = threadIdx.x;
    int r0 = blockIdx.x * 64;
    const float4* x4 = (const float4*)x;
#pragma unroll
    for (int it = 0; it < 8; ++it) {
        int i = tid + (it << 8);
        int row = i >> 5, c4 = i & 31;
        float4 v = {0.f, 0.f, 0.f, 0.f};
        if (r0 + row < N_NODES) v = x4[(size_t)(r0 + row) * 32 + c4];
        xs[row * 68 + c4 * 2]     = pack_bf16x2(v.x, v.y);
        xs[row * 68 + c4 * 2 + 1] = pack_bf16x2(v.z, v.w);
    }
    __syncthreads();
    int wave = tid >> 6, lane = tid & 63;
    int r0w = r0 + wave * 16;
    if (r0w >= N_NODES) return;
    int m = lane & 15, q = lane >> 4;
    bf16x8 afrag[4];
#pragma unroll
    for (int kt = 0; kt < 4; ++kt)
        afrag[kt] = *(const bf16x8*)&xs[(wave * 16 + m) * 68 + kt * 16 + q * 4];
    const uint4* B4 = (const uint4*)WTg;
    int bbase = m * 16 + q;
    f32x4 acc[8];
#pragma unroll
    for (int nt = 0; nt < 8; ++nt)
        acc[nt][0] = acc[nt][1] = acc[nt][2] = acc[nt][3] = 0.f;
#pragma unroll
    for (int nt = 0; nt < 8; ++nt) {
#pragma unroll
        for (int kt = 0; kt < 4; ++kt) {
            uint4 braw = B4[nt * 256 + kt * 4 + bbase];
            bf16x8 bfrag = __builtin_bit_cast(bf16x8, braw);
            acc[nt] = __builtin_amdgcn_mfma_f32_16x16x32_bf16(afrag[kt], bfrag, acc[nt], 0, 0, 0);
        }
    }
    int rb = r0w + q * 4;
    float dv[4];
#pragma unroll
    for (int reg = 0; reg < 4; ++reg) dv[reg] = rsqrtf((float)cnt[rb + reg] + 1.f);
#pragma unroll
    for (int nt = 0; nt < 8; ++nt) {
        int cbase = nt * 16 + m;
#pragma unroll
        for (int reg = 0; reg < 4; ++reg)
            g[(size_t)(rb + reg) * C + cbase] = bf16_1(acc[nt][reg] * dv[reg]);
    }
}

// ---- gather: 16 lanes per node, 4 nodes per wave, uint4 row segments ----
// g row = 16 uint4 (256 B); lane l holds dwords 4l..4l+3 = channels 8l..8l+7.
__global__ void __launch_bounds__(256) k_gather(const int* __restrict__ offs,
                                                const unsigned short* __restrict__ srcs,
                                                const uint4* __restrict__ g4,
                                                float* __restrict__ agg) {
    int t = threadIdx.x;
    int node = blockIdx.x * 16 + (t >> 4);
    if (node >= N_NODES) return;
    int l = t & 15;          // lane within quarter
    int qb = t & 48;         // quarter base within wave (0,16,32,48)
    int beg = offs[node], end = offs[node + 1];
    uint4 u = g4[(size_t)node * 16 + l];  // self-loop term
    float a0[8], a1[8], a2[8], a3[8];
    a0[0] = blo(u.x); a0[1] = bhi(u.x); a0[2] = blo(u.y); a0[3] = bhi(u.y);
    a0[4] = blo(u.z); a0[5] = bhi(u.z); a0[6] = blo(u.w); a0[7] = bhi(u.w);
#pragma unroll
    for (int i = 0; i < 8; ++i) { a1[i] = 0.f; a2[i] = 0.f; a3[i] = 0.f; }
    for (int base = beg; base < end; base += 16) {
        int m = end - base; if (m > 16) m = 16;
        int sv = (base + l < end) ? (int)srcs[base + l] : 0;  // 16-wide batch
        int j = 0;
        for (; j + 3 < m; j += 4) {
            int s0 = __shfl(sv, qb + j, 64);
            int s1 = __shfl(sv, qb + j + 1, 64);
            int s2 = __shfl(sv, qb + j + 2, 64);
            int s3 = __shfl(sv, qb + j + 3, 64);
            uint4 v0 = g4[(size_t)s0 * 16 + l];
            uint4 v1 = g4[(size_t)s1 * 16 + l];
            uint4 v2 = g4[(size_t)s2 * 16 + l];
            uint4 v3 = g4[(size_t)s3 * 16 + l];
            a0[0] += blo(v0.x); a0[1] += bhi(v0.x); a0[2] += blo(v0.y); a0[3] += bhi(v0.y);
            a0[4] += blo(v0.z); a0[5] += bhi(v0.z); a0[6] += blo(v0.w); a0[7] += bhi(v0.w);
            a1[0] += blo(v1.x); a1[1] += bhi(v1.x); a1[2] += blo(v1.y); a1[3] += bhi(v1.y);
            a1[4] += blo(v1.z); a1[5] += bhi(v1.z); a1[6] += blo(v1.w); a1[7] += bhi(v1.w);
            a2[0] += blo(v2.x); a2[1] += bhi(v2.x); a2[2] += blo(v2.y); a2[3] += bhi(v2.y);
            a2[4] += blo(v2.z); a2[5] += bhi(v2.z); a2[6] += blo(v2.w); a2[7] += bhi(v2.w);
            a3[0] += blo(v3.x); a3[1] += bhi(v3.x); a3[2] += blo(v3.y); a3[3] += bhi(v3.y);
            a3[4] += blo(v3.z); a3[5] += bhi(v3.z); a3[6] += blo(v3.w); a3[7] += bhi(v3.w);
        }
        for (; j < m; ++j) {
            int s0 = __shfl(sv, qb + j, 64);
            uint4 v0 = g4[(size_t)s0 * 16 + l];
            a0[0] += blo(v0.x); a0[1] += bhi(v0.x); a0[2] += blo(v0.y); a0[3] += bhi(v0.y);
            a0[4] += blo(v0.z); a0[5] += bhi(v0.z); a0[6] += blo(v0.w); a0[7] += bhi(v0.w);
        }
    }
    float dt = rsqrtf((float)(end - beg) + 1.f);
    float4 o0, o1;
    o0.x = (a0[0] + a1[0] + a2[0] + a3[0]) * dt;
    o0.y = (a0[1] + a1[1] + a2[1] + a3[1]) * dt;
    o0.z = (a0[2] + a1[2] + a2[2] + a3[2]) * dt;
    o0.w = (a0[3] + a1[3] + a2[3] + a3[3]) * dt;
    o1.x = (a0[4] + a1[4] + a2[4] + a3[4]) * dt;
    o1.y = (a0[5] + a1[5] + a2[5] + a3[5]) * dt;
    o1.z = (a0[6] + a1[6] + a2[6] + a3[6]) * dt;
    o1.w = (a0[7] + a1[7] + a2[7] + a3[7]) * dt;
    float4* out = (float4*)(agg + (size_t)node * C + l * 8);
    out[0] = o0; out[1] = o1;
}

// ---- per-channel sum / sumsq over nodes ----
__global__ void __launch_bounds__(256) k_stats(const float* __restrict__ agg,
                                               float* __restrict__ sums,
                                               float* __restrict__ sumsq) {
    int tx = threadIdx.x;
    int r = blockIdx.x * 8 + threadIdx.y;
    int stride = gridDim.x * 8;
    const float4* a4 = (const float4*)agg;
    float4 s = {0,0,0,0}, q = {0,0,0,0};
    for (; r < N_NODES; r += stride) {
        float4 v = a4[(size_t)r * 32 + tx];
        s.x += v.x; s.y += v.y; s.z += v.z; s.w += v.w;
        q.x += v.x * v.x; q.y += v.y * v.y; q.z += v.z * v.z; q.w += v.w * v.w;
    }
    __shared__ float4 ls[8][32], lq[8][32];
    ls[threadIdx.y][tx] = s; lq[threadIdx.y][tx] = q;
    __syncthreads();
    if (threadIdx.y == 0) {
        for (int w = 1; w < 8; ++w) {
            float4 v = ls[w][tx], u = lq[w][tx];
            s.x += v.x; s.y += v.y; s.z += v.z; s.w += v.w;
            q.x += u.x; q.y += u.y; q.z += u.z; q.w += u.w;
        }
        int c = tx * 4;
        atomicAdd(&sums[c + 0], s.x); atomicAdd(&sums[c + 1], s.y);
        atomicAdd(&sums[c + 2], s.z); atomicAdd(&sums[c + 3], s.w);
        atomicAdd(&sumsq[c + 0], q.x); atomicAdd(&sumsq[c + 1], q.y);
        atomicAdd(&sumsq[c + 2], q.z); atomicAdd(&sumsq[c + 3], q.w);
    }
}

// ---- y = relu(agg*scale + shift); bias cancels in BN ----
__global__ void __launch_bounds__(256) k_final(float* __restrict__ agg,
                                               const float* __restrict__ sums,
                                               const float* __restrict__ sumsq,
                                               const float* __restrict__ gamma,
                                               const float* __restrict__ beta) {
    __shared__ float sc_s[C], sh_s[C];
    int tid = threadIdx.x;
    if (tid < C) {
        float mean = sums[tid] * (1.0f / N_NODES);
        float var = sumsq[tid] * (1.0f / N_NODES) - mean * mean;
        float sc = gamma[tid] * rsqrtf(var + BN_EPS);
        sc_s[tid] = sc;
        sh_s[tid] = beta[tid] - mean * sc;
    }
    __syncthreads();
    int i = blockIdx.x * 256 + tid;
    if (i >= N_NODES * 32) return;
    int c = (i & 31) * 4;
    float4 v = ((float4*)agg)[i];
    v.x = fmaxf(v.x * sc_s[c + 0] + sh_s[c + 0], 0.f);
    v.y = fmaxf(v.y * sc_s[c + 1] + sh_s[c + 1], 0.f);
    v.z = fmaxf(v.z * sc_s[c + 2] + sh_s[c + 2], 0.f);
    v.w = fmaxf(v.w * sc_s[c + 3] + sh_s[c + 3], 0.f);
    ((float4*)agg)[i] = v;
}

extern "C" void kernel_launch(void* const* d_in, const int* in_sizes, int n_in,
                              void* d_out, int out_size, void* d_ws, size_t ws_size,
                              hipStream_t stream) {
    const float* x     = (const float*)d_in[0];
    const float* W     = (const float*)d_in[1];
    // d_in[2] = bias: cancels in BatchNorm, unused
    const float* gamma = (const float*)d_in[3];
    const float* beta  = (const float*)d_in[4];
    const int*   eidx  = (const int*)d_in[5];
    const int* row = eidx;
    const int* col = eidx + N_EDGES;

    float* agg = (float*)d_out;  // [N, C], finalized in place

    // workspace layout
    unsigned* g      = (unsigned*)d_ws;                  // [N*64] bf16x2
    unsigned* bEdges = g + (size_t)N_NODES * 64;         // [E] packed src|dst<<16
    int*   cnt    = (int*)(bEdges + N_EDGES);            // [N]
    int*   offs   = cnt + N_NODES;                       // [N+1]
    float* sums   = (float*)(offs + N_NODES + 1);        // [C]   (zeroed by k_bscan)
    float* sumsq  = sums + C;                            // [C]   (zeroed by k_bscan)
    int*   bStart = (int*)(sumsq + C);                   // [NBUCK+1]
    int*   bCur   = bStart + NBUCK + 1;                  // [NBUCK]
    int*   bHistG = bCur + NBUCK;                        // [A_BLOCKS*NBUCK]
    unsigned* WTg = (unsigned*)(bHistG + A_BLOCKS * NBUCK); // [128*64] bf16x2 (W^T)
    unsigned short* srcs = (unsigned short*)(WTg + 128 * 64); // [E] u16

    k_bhist<<<A_BLOCKS, 256, 0, stream>>>(col, bHistG, W, WTg);
    k_bscan<<<1, 512, 0, stream>>>(bHistG, bStart, bCur, offs, sums);
    k_bscatter<<<A_BLOCKS, 256, 0, stream>>>(row, col, bHistG, bCur, bEdges);
    k_bsort<<<NBUCK, 256, 0, stream>>>(bEdges, bStart, offs, cnt, srcs);
    k_gemm<<<(N_NODES + 63) / 64, 256, 0, stream>>>(x, WTg, cnt, (unsigned short*)g);
    k_gather<<<(N_NODES + 15) / 16, 256, 0, stream>>>(offs, srcs, (const uint4*)g, agg);
    k_stats<<<256, dim3(32, 8), 0, stream>>>(agg, sums, sumsq);
    k_final<<<(N_NODES * 32 + 255) / 256, 256, 0, stream>>>(agg, sums, sumsq, gamma, beta);
}